// Round 1
// baseline (1402.221 us; speedup 1.0000x reference)
//
#include <hip/hip_runtime.h>
#include <math.h>

// Problem constants (MultiHeadAttention_15341623181946)
#define NB 8          // batch
#define SS 1024       // sequence
#define NH 16         // heads
#define DK 64         // head dim
#define EE 1024       // NH*DK
#define DMOD 1024     // d_model

// ---------------------------------------------------------------------------
// Generic f32 GEMM: C = A[M,K] @ W[N,K]^T + bias[N]   (torch Linear semantics)
// OUTMAP 0: C row-major [M,N]
// OUTMAP 1: scatter to [b][h][s][d] with r=b*1024+s, n=h*64+d (projection split)
// ---------------------------------------------------------------------------
template<int OUTMAP, bool RELU>
__global__ __launch_bounds__(256) void gemm_bias_kernel(
    const float* __restrict__ A, const float* __restrict__ W,
    const float* __restrict__ bias, float* __restrict__ C,
    int M, int N, int K)
{
    __shared__ float At[64][68];   // [k][m] transposed, pitch 68 (16B-aligned rows)
    __shared__ float Bt[64][68];   // [k][n] transposed
    const int tid = threadIdx.x;
    const int n0 = blockIdx.x * 64;
    const int m0 = blockIdx.y * 64;
    const int rh = tid >> 4;       // staging: row-group 0..15
    const int lq = tid & 15;       // staging: float4 index within row
    const int ty = tid >> 4;       // compute: owns rows ty*4..ty*4+3
    const int tx = tid & 15;       // compute: owns cols tx*4..tx*4+3

    float acc[4][4] = {};

    for (int kt = 0; kt < K; kt += 64) {
        __syncthreads();           // protect LDS from previous iteration's readers
        #pragma unroll
        for (int rr = 0; rr < 4; ++rr) {
            const int row = rr * 16 + rh;   // 0..63
            const float4 av = *(const float4*)(A + (size_t)(m0 + row) * K + kt + lq * 4);
            const float4 wv = *(const float4*)(W + (size_t)(n0 + row) * K + kt + lq * 4);
            At[lq*4+0][row] = av.x; At[lq*4+1][row] = av.y;
            At[lq*4+2][row] = av.z; At[lq*4+3][row] = av.w;
            Bt[lq*4+0][row] = wv.x; Bt[lq*4+1][row] = wv.y;
            Bt[lq*4+2][row] = wv.z; Bt[lq*4+3][row] = wv.w;
        }
        __syncthreads();
        #pragma unroll 8
        for (int c = 0; c < 64; ++c) {
            const float4 a4 = *(const float4*)&At[c][ty * 4];
            const float4 b4 = *(const float4*)&Bt[c][tx * 4];
            const float av2[4] = {a4.x, a4.y, a4.z, a4.w};
            const float bv2[4] = {b4.x, b4.y, b4.z, b4.w};
            #pragma unroll
            for (int i = 0; i < 4; ++i)
                #pragma unroll
                for (int j = 0; j < 4; ++j)
                    acc[i][j] = fmaf(av2[i], bv2[j], acc[i][j]);
        }
    }

    const float4 bv = *(const float4*)(bias + n0 + tx * 4);
    const float bb[4] = {bv.x, bv.y, bv.z, bv.w};
    #pragma unroll
    for (int i = 0; i < 4; ++i) {
        const int r = m0 + ty * 4 + i;
        float ov[4];
        #pragma unroll
        for (int j = 0; j < 4; ++j) {
            float val = acc[i][j] + bb[j];
            if (RELU) val = fmaxf(val, 0.0f);
            ov[j] = val;
        }
        float4 o4; o4.x = ov[0]; o4.y = ov[1]; o4.z = ov[2]; o4.w = ov[3];
        const int n = n0 + tx * 4;
        if (OUTMAP == 0) {
            *(float4*)(C + (size_t)r * N + n) = o4;
        } else {
            // [b][h][s][d]: b=r>>10, s=r&1023, h=n>>6, d=n&63 (d contiguous -> float4 ok)
            const size_t idx = ((size_t)((r >> 10) * NH + (n >> 6))) * 65536
                             + (size_t)(r & 1023) * 64 + (n & 63);
            *(float4*)(C + idx) = o4;
        }
    }
}

// ---------------------------------------------------------------------------
// Flash-style attention, f32. One block = one (b,h) and 64 q-rows.
// Thread layout: qr = tid>>2 (q-row in tile), sub = tid&3.
//   scores: thread owns k = kk*4+sub (kk=0..15)  [avoids LDS bank conflicts]
//   PV:     thread owns output dims d = sub*16 .. sub*16+15
// Online softmax state (m,l) replicated across the 4 sub-lanes via shuffles.
// ---------------------------------------------------------------------------
__global__ __launch_bounds__(256) void attn_kernel(
    const float* __restrict__ Qp, const float* __restrict__ Kp,
    const float* __restrict__ Vp, float* __restrict__ Y)
{
    __shared__ float Qs[64][68];
    __shared__ float Ks[64][68];
    __shared__ float Vs[64][68];
    __shared__ float Ps[64][68];
    const int tid = threadIdx.x;
    const int q0 = blockIdx.x * 64;
    const int h  = blockIdx.y;
    const int b  = blockIdx.z;
    const size_t base = (size_t)(b * NH + h) * (SS * DK);
    const int rh = tid >> 4;
    const int lq = tid & 15;

    #pragma unroll
    for (int rr = 0; rr < 4; ++rr) {
        const int row = rr * 16 + rh;
        const float4 qv = *(const float4*)(Qp + base + (size_t)(q0 + row) * DK + lq * 4);
        *(float4*)&Qs[row][lq * 4] = qv;
    }

    const int qr  = tid >> 2;
    const int sub = tid & 3;
    float m = -1e30f, l = 0.0f;
    float4 o[4] = {};

    for (int kt = 0; kt < 16; ++kt) {
        __syncthreads();   // previous PV readers done before K/V overwrite
        #pragma unroll
        for (int rr = 0; rr < 4; ++rr) {
            const int row = rr * 16 + rh;
            const float4 kv = *(const float4*)(Kp + base + (size_t)(kt * 64 + row) * DK + lq * 4);
            *(float4*)&Ks[row][lq * 4] = kv;
            const float4 vv = *(const float4*)(Vp + base + (size_t)(kt * 64 + row) * DK + lq * 4);
            *(float4*)&Vs[row][lq * 4] = vv;
        }
        __syncthreads();

        // --- scores: s[kk] = Q[qr,:] . K[kk*4+sub,:] ---
        float s[16];
        #pragma unroll
        for (int i = 0; i < 16; ++i) s[i] = 0.0f;
        #pragma unroll 4
        for (int dq = 0; dq < 16; ++dq) {
            const float4 qv = *(const float4*)&Qs[qr][dq * 4];
            #pragma unroll
            for (int kk = 0; kk < 16; ++kk) {
                const float4 kv = *(const float4*)&Ks[kk * 4 + sub][dq * 4];
                s[kk] = fmaf(qv.x, kv.x, s[kk]);
                s[kk] = fmaf(qv.y, kv.y, s[kk]);
                s[kk] = fmaf(qv.z, kv.z, s[kk]);
                s[kk] = fmaf(qv.w, kv.w, s[kk]);
            }
        }

        // --- online softmax update ---
        float sm = -1e30f;
        #pragma unroll
        for (int i = 0; i < 16; ++i) { s[i] *= 0.125f; sm = fmaxf(sm, s[i]); }
        sm = fmaxf(sm, __shfl_xor(sm, 1));
        sm = fmaxf(sm, __shfl_xor(sm, 2));
        const float mnew  = fmaxf(m, sm);
        const float alpha = __expf(m - mnew);
        float ls = 0.0f;
        #pragma unroll
        for (int i = 0; i < 16; ++i) { s[i] = __expf(s[i] - mnew); ls += s[i]; }
        ls += __shfl_xor(ls, 1);
        ls += __shfl_xor(ls, 2);
        l = l * alpha + ls;
        m = mnew;
        #pragma unroll
        for (int c = 0; c < 4; ++c) {
            o[c].x *= alpha; o[c].y *= alpha; o[c].z *= alpha; o[c].w *= alpha;
        }
        #pragma unroll
        for (int i = 0; i < 16; ++i) Ps[qr][i * 4 + sub] = s[i];
        __syncthreads();

        // --- PV: O[d] += sum_j P[qr][j] * V[j][d], d in sub*16..+15 ---
        #pragma unroll 8
        for (int j = 0; j < 64; ++j) {
            const float pj = Ps[qr][j];
            #pragma unroll
            for (int c = 0; c < 4; ++c) {
                const float4 vv = *(const float4*)&Vs[j][sub * 16 + c * 4];
                o[c].x = fmaf(pj, vv.x, o[c].x);
                o[c].y = fmaf(pj, vv.y, o[c].y);
                o[c].z = fmaf(pj, vv.z, o[c].z);
                o[c].w = fmaf(pj, vv.w, o[c].w);
            }
        }
    }

    const float inv = 1.0f / l;
    float* dst = Y + (size_t)(b * SS + q0 + qr) * EE + h * DK + sub * 16;
    #pragma unroll
    for (int c = 0; c < 4; ++c) {
        float4 ov = o[c];
        ov.x *= inv; ov.y *= inv; ov.z *= inv; ov.w *= inv;
        *(float4*)(dst + c * 4) = ov;
    }
}

// ---------------------------------------------------------------------------
// Workspace layout (floats):
//   Qp: ws[0        .. 8388608)   [8][16][1024][64]
//   Kp: ws[8388608  .. 16777216)
//   Vp: ws[16777216 .. 25165824)
//   Y  -> uses d_out as scratch (attention output, consumed by MLP1)
//   H1 -> reuses Qp region (projections dead after attention)
// Peak ws need: 3 * 33.55 MB = 100.7 MB.
// ---------------------------------------------------------------------------
extern "C" void kernel_launch(void* const* d_in, const int* in_sizes, int n_in,
                              void* d_out, int out_size, void* d_ws, size_t ws_size,
                              hipStream_t stream) {
    const float* q  = (const float*)d_in[0];
    const float* k  = (const float*)d_in[1];
    const float* v  = (const float*)d_in[2];
    const float* Wq = (const float*)d_in[3];
    const float* bq = (const float*)d_in[4];
    const float* W1 = (const float*)d_in[5];
    const float* b1 = (const float*)d_in[6];
    const float* W2 = (const float*)d_in[7];
    const float* b2 = (const float*)d_in[8];
    float* out = (float*)d_out;
    float* ws  = (float*)d_ws;

    float* Qp = ws;
    float* Kp = ws + (size_t)8388608;
    float* Vp = ws + (size_t)16777216;
    float* Y  = out;   // d_out doubles as attention-output scratch
    float* H1 = ws;    // reuse Qp region after attention

    dim3 blk(256, 1, 1);

    // Projections (shared weight Wq applied to q, k, v)
    dim3 gp(EE / 64, (NB * SS) / 64, 1);
    gemm_bias_kernel<1, false><<<gp, blk, 0, stream>>>(q, Wq, bq, Qp, NB * SS, EE, DK);
    gemm_bias_kernel<1, false><<<gp, blk, 0, stream>>>(k, Wq, bq, Kp, NB * SS, EE, DK);
    gemm_bias_kernel<1, false><<<gp, blk, 0, stream>>>(v, Wq, bq, Vp, NB * SS, EE, DK);

    // Attention
    dim3 ga(SS / 64, NH, NB);
    attn_kernel<<<ga, blk, 0, stream>>>(Qp, Kp, Vp, Y);

    // Output MLP: Linear -> ReLU -> Linear
    dim3 gm(DMOD / 64, (NB * SS) / 64, 1);
    gemm_bias_kernel<0, true ><<<gm, blk, 0, stream>>>(Y,  W1, b1, H1,  NB * SS, DMOD, EE);
    gemm_bias_kernel<0, false><<<gm, blk, 0, stream>>>(H1, W2, b2, out, NB * SS, DMOD, DMOD);
}

// Round 2
// 251.239 us; speedup vs baseline: 5.5812x; 5.5812x over previous
//
#include <hip/hip_runtime.h>
#include <math.h>

// Problem constants (MultiHeadAttention_15341623181946)
#define NB 8          // batch
#define SS 1024       // sequence
#define NH 16         // heads
#define DK 64         // head dim
#define EE 1024       // NH*DK
#define DMOD 1024     // d_model

using bf16x8 = __attribute__((ext_vector_type(8))) short;   // 8 bf16 = 4 VGPR
using f32x4  = __attribute__((ext_vector_type(4))) float;   // MFMA acc

__device__ __forceinline__ unsigned short f2bf(float f) {
    unsigned u = __builtin_bit_cast(unsigned, f);
    u += 0x7FFFu + ((u >> 16) & 1u);        // round-to-nearest-even
    return (unsigned short)(u >> 16);
}

// ---------------------------------------------------------------------------
// Projection GEMM: C_bf16[b][h][s][d] = A[M,64] @ Wq[1024,64]^T + bq
// f32 compute (K=64 only, ~1 GFLOP). M=8192, N=1024, K=64.
// ---------------------------------------------------------------------------
__global__ __launch_bounds__(256) void proj_gemm(
    const float* __restrict__ A, const float* __restrict__ W,
    const float* __restrict__ bias, unsigned short* __restrict__ C)
{
    __shared__ float At[64][68];   // [k][m]
    __shared__ float Bt[64][68];   // [k][n]
    const int tid = threadIdx.x;
    const int n0 = blockIdx.x * 64;
    const int m0 = blockIdx.y * 64;
    const int rh = tid >> 4, lq = tid & 15;
    const int ty = tid >> 4, tx = tid & 15;

    float acc[4][4] = {};
    #pragma unroll
    for (int rr = 0; rr < 4; ++rr) {
        const int row = rr * 16 + rh;
        const float4 av = *(const float4*)(A + (size_t)(m0 + row) * DK + lq * 4);
        const float4 wv = *(const float4*)(W + (size_t)(n0 + row) * DK + lq * 4);
        At[lq*4+0][row] = av.x; At[lq*4+1][row] = av.y;
        At[lq*4+2][row] = av.z; At[lq*4+3][row] = av.w;
        Bt[lq*4+0][row] = wv.x; Bt[lq*4+1][row] = wv.y;
        Bt[lq*4+2][row] = wv.z; Bt[lq*4+3][row] = wv.w;
    }
    __syncthreads();
    #pragma unroll 8
    for (int c = 0; c < 64; ++c) {
        const float4 a4 = *(const float4*)&At[c][ty * 4];
        const float4 b4 = *(const float4*)&Bt[c][tx * 4];
        const float av2[4] = {a4.x, a4.y, a4.z, a4.w};
        const float bv2[4] = {b4.x, b4.y, b4.z, b4.w};
        #pragma unroll
        for (int i = 0; i < 4; ++i)
            #pragma unroll
            for (int j = 0; j < 4; ++j)
                acc[i][j] = fmaf(av2[i], bv2[j], acc[i][j]);
    }
    const float4 bv = *(const float4*)(bias + n0 + tx * 4);
    const float bb[4] = {bv.x, bv.y, bv.z, bv.w};
    #pragma unroll
    for (int i = 0; i < 4; ++i) {
        const int r = m0 + ty * 4 + i;
        const int n = n0 + tx * 4;
        // [b][h][s][d]
        const size_t idx = ((size_t)((r >> 10) * NH + (n >> 6))) * 65536
                         + (size_t)(r & 1023) * 64 + (n & 63);
        ushort4 o;
        o.x = f2bf(acc[i][0] + bb[0]); o.y = f2bf(acc[i][1] + bb[1]);
        o.z = f2bf(acc[i][2] + bb[2]); o.w = f2bf(acc[i][3] + bb[3]);
        *(ushort4*)(C + idx) = o;
    }
}

// ---------------------------------------------------------------------------
// f32 -> bf16 conversion (for W1, W2)
// ---------------------------------------------------------------------------
__global__ __launch_bounds__(256) void cvt_bf16(
    const float* __restrict__ s, unsigned short* __restrict__ d, int n)
{
    const int i = (blockIdx.x * 256 + threadIdx.x) * 8;
    if (i >= n) return;
    const float4 a = *(const float4*)(s + i);
    const float4 b = *(const float4*)(s + i + 4);
    bf16x8 o;
    o[0]=(short)f2bf(a.x); o[1]=(short)f2bf(a.y); o[2]=(short)f2bf(a.z); o[3]=(short)f2bf(a.w);
    o[4]=(short)f2bf(b.x); o[5]=(short)f2bf(b.y); o[6]=(short)f2bf(b.z); o[7]=(short)f2bf(b.w);
    *(bf16x8*)(d + i) = o;
}

// ---------------------------------------------------------------------------
// Vp[b][h][s][d] -> Vt[b][h][d][s]  (bf16, per-head 1024x64 -> 64x1024)
// ---------------------------------------------------------------------------
__global__ __launch_bounds__(256) void transpose_v(
    const unsigned short* __restrict__ Vp, unsigned short* __restrict__ Vt)
{
    __shared__ __align__(16) unsigned short T[64][72];
    const int bh = blockIdx.y;
    const int s0 = blockIdx.x * 64;
    const size_t base = (size_t)bh * (SS * DK);
    const int tid = threadIdx.x;
    #pragma unroll
    for (int i = 0; i < 2; ++i) {
        const int c = i * 256 + tid;
        const int row = c >> 3, cq = (c & 7) * 8;
        *(bf16x8*)&T[row][cq] = *(const bf16x8*)(Vp + base + (size_t)(s0 + row) * DK + cq);
    }
    __syncthreads();
    #pragma unroll
    for (int i = 0; i < 2; ++i) {
        const int c = i * 256 + tid;
        const int d = c >> 3, sq = (c & 7) * 8;
        bf16x8 v;
        #pragma unroll
        for (int j = 0; j < 8; ++j) v[j] = (short)T[sq + j][d];
        *(bf16x8*)(Vt + base + (size_t)d * SS + s0 + sq) = v;
    }
}

// ---------------------------------------------------------------------------
// Flash attention, bf16 MFMA. Block = (b,h) x 64 q-rows, 4 waves (16 q each).
// KV tiles of 64. QK^T and PV via mfma_f32_16x16x32_bf16, f32 accum.
// A-frag: lane holds A[lane&15][ (lane>>4)*8 + j + 32*kk ]
// B-frag: lane holds B^T[n=lane&15][ k=(lane>>4)*8 + j ] (row-major [n][k] read)
// C/D  : lane holds C[(lane>>4)*4 + r][lane&15]
// ---------------------------------------------------------------------------
__global__ __launch_bounds__(256) void attn_mfma(
    const unsigned short* __restrict__ Qp, const unsigned short* __restrict__ Kp,
    const unsigned short* __restrict__ Vt, unsigned short* __restrict__ Y)
{
    __shared__ __align__(16) unsigned short Qs[64][72];
    __shared__ __align__(16) unsigned short Ks[64][72];
    __shared__ __align__(16) unsigned short Vs[64][72];   // Vt rows: [d][k]
    __shared__ __align__(16) unsigned short Ps[4][16][72]; // per-wave P [q][k]
    const int tid  = threadIdx.x;
    const int lane = tid & 63;
    const int w    = tid >> 6;
    const int q0   = blockIdx.x * 64;
    const size_t base = (size_t)(blockIdx.z * NH + blockIdx.y) * (SS * DK);
    const int lr = lane & 15, lg = lane >> 4;

    #pragma unroll
    for (int i = 0; i < 2; ++i) {
        const int c = i * 256 + tid;
        const int row = c >> 3, cq = (c & 7) * 8;
        *(bf16x8*)&Qs[row][cq] = *(const bf16x8*)(Qp + base + (size_t)(q0 + row) * DK + cq);
    }
    __syncthreads();
    const bf16x8 aQ0 = *(const bf16x8*)&Qs[w * 16 + lr][lg * 8];
    const bf16x8 aQ1 = *(const bf16x8*)&Qs[w * 16 + lr][32 + lg * 8];

    float mrow[4], lrow[4];
    #pragma unroll
    for (int r = 0; r < 4; ++r) { mrow[r] = -1e30f; lrow[r] = 0.0f; }
    f32x4 oacc[4] = {};

    for (int kt = 0; kt < 16; ++kt) {
        __syncthreads();   // previous tile's readers done
        #pragma unroll
        for (int i = 0; i < 2; ++i) {
            const int c = i * 256 + tid;
            const int row = c >> 3, cq = (c & 7) * 8;
            *(bf16x8*)&Ks[row][cq] = *(const bf16x8*)(Kp + base + (size_t)(kt * 64 + row) * DK + cq);
            *(bf16x8*)&Vs[row][cq] = *(const bf16x8*)(Vt + base + (size_t)row * SS + kt * 64 + cq);
        }
        __syncthreads();

        // --- QK^T: S[16q][64k] per wave ---
        f32x4 sacc[4] = {};
        #pragma unroll
        for (int nb = 0; nb < 4; ++nb) {
            const bf16x8 bk0 = *(const bf16x8*)&Ks[nb * 16 + lr][lg * 8];
            const bf16x8 bk1 = *(const bf16x8*)&Ks[nb * 16 + lr][32 + lg * 8];
            sacc[nb] = __builtin_amdgcn_mfma_f32_16x16x32_bf16(aQ0, bk0, sacc[nb], 0, 0, 0);
            sacc[nb] = __builtin_amdgcn_mfma_f32_16x16x32_bf16(aQ1, bk1, sacc[nb], 0, 0, 0);
        }

        // --- online softmax (rows r=0..3; row q = w*16 + lg*4 + r) ---
        float pnew[4][4];
        #pragma unroll
        for (int r = 0; r < 4; ++r) {
            float mx = fmaxf(fmaxf(sacc[0][r], sacc[1][r]), fmaxf(sacc[2][r], sacc[3][r]));
            mx = fmaxf(mx, __shfl_xor(mx, 1));
            mx = fmaxf(mx, __shfl_xor(mx, 2));
            mx = fmaxf(mx, __shfl_xor(mx, 4));
            mx = fmaxf(mx, __shfl_xor(mx, 8));
            mx *= 0.125f;                       // scale = 1/sqrt(64)
            const float mn = fmaxf(mrow[r], mx);
            const float alpha = __expf(mrow[r] - mn);
            float ls = 0.0f;
            #pragma unroll
            for (int nb = 0; nb < 4; ++nb) {
                const float p = __expf(fmaf(sacc[nb][r], 0.125f, -mn));
                pnew[nb][r] = p; ls += p;
            }
            ls += __shfl_xor(ls, 1);
            ls += __shfl_xor(ls, 2);
            ls += __shfl_xor(ls, 4);
            ls += __shfl_xor(ls, 8);
            mrow[r] = mn;
            lrow[r] = fmaf(lrow[r], alpha, ls);
            #pragma unroll
            for (int d0 = 0; d0 < 4; ++d0) oacc[d0][r] *= alpha;
        }

        // --- P -> LDS (bf16) for A-operand transpose ---
        #pragma unroll
        for (int nb = 0; nb < 4; ++nb)
            #pragma unroll
            for (int r = 0; r < 4; ++r)
                Ps[w][lg * 4 + r][nb * 16 + lr] = f2bf(pnew[nb][r]);

        // --- PV: O[16q][64d] += P[16][64] x V[64][64] ---
        #pragma unroll
        for (int kk = 0; kk < 2; ++kk) {
            const bf16x8 aP = *(const bf16x8*)&Ps[w][lr][kk * 32 + lg * 8];
            #pragma unroll
            for (int d0 = 0; d0 < 4; ++d0) {
                const bf16x8 bv = *(const bf16x8*)&Vs[d0 * 16 + lr][kk * 32 + lg * 8];
                oacc[d0] = __builtin_amdgcn_mfma_f32_16x16x32_bf16(aP, bv, oacc[d0], 0, 0, 0);
            }
        }
    }

    // epilogue: Y[b][s][h*64+d] bf16
    #pragma unroll
    for (int r = 0; r < 4; ++r) {
        const float inv = 1.0f / lrow[r];
        const int q = q0 + w * 16 + lg * 4 + r;
        unsigned short* dst = Y + (size_t)(blockIdx.z * SS + q) * EE + blockIdx.y * DK;
        #pragma unroll
        for (int d0 = 0; d0 < 4; ++d0)
            dst[d0 * 16 + lr] = f2bf(oacc[d0][r] * inv);
    }
}

// ---------------------------------------------------------------------------
// MLP GEMM, bf16 MFMA: C[M,N] = A[M,K]_bf16 @ B[N,K]_bf16^T + bias (+ReLU)
// 128x128 tile, 4 waves (2x2 of 64x64), K-step 64, reg-staged padded LDS.
// ---------------------------------------------------------------------------
template<bool RELU, bool OUT_BF16>
__global__ __launch_bounds__(256) void mlp_gemm(
    const unsigned short* __restrict__ A, const unsigned short* __restrict__ B,
    const float* __restrict__ bias, void* __restrict__ Cv)
{
    const int K = 1024, N = 1024;
    __shared__ __align__(16) unsigned short As[128][72];
    __shared__ __align__(16) unsigned short Bs[128][72];
    const int tid  = threadIdx.x;
    const int lane = tid & 63;
    const int w = tid >> 6, wm = w >> 1, wn = w & 1;
    const int n0 = blockIdx.x * 128, m0 = blockIdx.y * 128;
    const int lr = lane & 15, lg = lane >> 4;

    f32x4 acc[4][4] = {};

    for (int kt = 0; kt < K; kt += 64) {
        __syncthreads();
        #pragma unroll
        for (int i = 0; i < 4; ++i) {
            const int c = i * 256 + tid;       // 0..1023
            const int row = c >> 3, cq = (c & 7) * 8;
            *(bf16x8*)&As[row][cq] = *(const bf16x8*)(A + (size_t)(m0 + row) * K + kt + cq);
            *(bf16x8*)&Bs[row][cq] = *(const bf16x8*)(B + (size_t)(n0 + row) * K + kt + cq);
        }
        __syncthreads();
        #pragma unroll
        for (int kk = 0; kk < 2; ++kk) {
            bf16x8 af[4], bfr[4];
            #pragma unroll
            for (int mf = 0; mf < 4; ++mf)
                af[mf] = *(const bf16x8*)&As[wm * 64 + mf * 16 + lr][kk * 32 + lg * 8];
            #pragma unroll
            for (int nf = 0; nf < 4; ++nf)
                bfr[nf] = *(const bf16x8*)&Bs[wn * 64 + nf * 16 + lr][kk * 32 + lg * 8];
            #pragma unroll
            for (int mf = 0; mf < 4; ++mf)
                #pragma unroll
                for (int nf = 0; nf < 4; ++nf)
                    acc[mf][nf] = __builtin_amdgcn_mfma_f32_16x16x32_bf16(
                        af[mf], bfr[nf], acc[mf][nf], 0, 0, 0);
        }
    }

    #pragma unroll
    for (int nf = 0; nf < 4; ++nf) {
        const int cc = n0 + wn * 64 + nf * 16 + lr;
        const float bb = bias[cc];
        #pragma unroll
        for (int mf = 0; mf < 4; ++mf) {
            #pragma unroll
            for (int r = 0; r < 4; ++r) {
                float x = acc[mf][nf][r] + bb;
                if (RELU) x = fmaxf(x, 0.0f);
                const size_t rr = (size_t)(m0 + wm * 64 + mf * 16 + lg * 4 + r);
                if (OUT_BF16) ((unsigned short*)Cv)[rr * N + cc] = f2bf(x);
                else          ((float*)Cv)[rr * N + cc] = x;
            }
        }
    }
}

// ---------------------------------------------------------------------------
// Workspace layout (ushort elements; 8.4M elems = 16.78 MB per tensor):
//   Qp : [0        , 8388608 )   -> reused as H1 after attention
//   Kp : [8388608  , 16777216)
//   Vp : [16777216 , 25165824)   -> reused as Y after transpose
//   Vt : [25165824 , 33554432)
//   W1b: [33554432 , 34603008)
//   W2b: [34603008 , 35651584)
// Total 71.3 MB.
// ---------------------------------------------------------------------------
extern "C" void kernel_launch(void* const* d_in, const int* in_sizes, int n_in,
                              void* d_out, int out_size, void* d_ws, size_t ws_size,
                              hipStream_t stream) {
    const float* q  = (const float*)d_in[0];
    const float* k  = (const float*)d_in[1];
    const float* v  = (const float*)d_in[2];
    const float* Wq = (const float*)d_in[3];
    const float* bq = (const float*)d_in[4];
    const float* W1 = (const float*)d_in[5];
    const float* b1 = (const float*)d_in[6];
    const float* W2 = (const float*)d_in[7];
    const float* b2 = (const float*)d_in[8];

    unsigned short* wsu = (unsigned short*)d_ws;
    unsigned short* Qp  = wsu;
    unsigned short* Kp  = wsu + (size_t)8388608;
    unsigned short* Vp  = wsu + (size_t)16777216;
    unsigned short* Vt  = wsu + (size_t)25165824;
    unsigned short* W1b = wsu + (size_t)33554432;
    unsigned short* W2b = wsu + (size_t)34603008;
    unsigned short* Y   = Vp;   // Vp dead after transpose
    unsigned short* H1  = Qp;   // Qp dead after attention

    dim3 blk(256);

    dim3 gp(EE / 64, (NB * SS) / 64);
    proj_gemm<<<gp, blk, 0, stream>>>(q, Wq, bq, Qp);
    proj_gemm<<<gp, blk, 0, stream>>>(k, Wq, bq, Kp);
    proj_gemm<<<gp, blk, 0, stream>>>(v, Wq, bq, Vp);

    cvt_bf16<<<512, blk, 0, stream>>>(W1, W1b, DMOD * EE);
    cvt_bf16<<<512, blk, 0, stream>>>(W2, W2b, DMOD * DMOD);

    transpose_v<<<dim3(16, 128), blk, 0, stream>>>(Vp, Vt);

    attn_mfma<<<dim3(16, 16, 8), blk, 0, stream>>>(Qp, Kp, Vt, Y);

    mlp_gemm<true,  true ><<<dim3(8, 64), blk, 0, stream>>>(Y,  W1b, b1, H1);
    mlp_gemm<false, false><<<dim3(8, 64), blk, 0, stream>>>(H1, W2b, b2, d_out);
}

// Round 3
// 207.312 us; speedup vs baseline: 6.7638x; 1.2119x over previous
//
#include <hip/hip_runtime.h>
#include <math.h>

// Problem constants (MultiHeadAttention_15341623181946)
#define NB 8          // batch
#define SS 1024       // sequence
#define NH 16         // heads
#define DK 64         // head dim
#define EE 1024       // NH*DK
#define DMOD 1024     // d_model

using bf16x8 = __attribute__((ext_vector_type(8))) short;   // 8 bf16 = 4 VGPR
using f32x4  = __attribute__((ext_vector_type(4))) float;   // MFMA acc

__device__ __forceinline__ unsigned short f2bf(float f) {
    unsigned u = __builtin_bit_cast(unsigned, f);
    u += 0x7FFFu + ((u >> 16) & 1u);        // round-to-nearest-even
    return (unsigned short)(u >> 16);
}

__device__ __forceinline__ float exp2_hw(float x) {
#if __has_builtin(__builtin_amdgcn_exp2f)
    return __builtin_amdgcn_exp2f(x);
#else
    float r; asm("v_exp_f32 %0, %1" : "=v"(r) : "v"(x)); return r;
#endif
}

__device__ __forceinline__ unsigned cvt_pk_bf16(float lo, float hi) {
    unsigned r;
    asm("v_cvt_pk_bf16_f32 %0, %1, %2" : "=v"(r) : "v"(lo), "v"(hi));
    return r;
}

// ---------------------------------------------------------------------------
// Batched projection GEMM (z = 0:q, 1:k, 2:v), shared weight Wq.
// C_bf16[b][h][s][d] = (A[M,64] @ Wq[1024,64]^T + bq) * (z==0 ? qscale : 1)
// qscale folds softmax 1/sqrt(dk) AND log2(e) so attn can use v_exp_f32.
// ---------------------------------------------------------------------------
__global__ __launch_bounds__(256) void proj_gemm(
    const float* __restrict__ q, const float* __restrict__ k,
    const float* __restrict__ v, const float* __restrict__ W,
    const float* __restrict__ bias, unsigned short* __restrict__ Cbase,
    float qscale)
{
    __shared__ float At[64][68];   // [k][m]
    __shared__ float Bt[64][68];   // [k][n]
    const int z = blockIdx.z;
    const float* A = (z == 0) ? q : (z == 1) ? k : v;
    unsigned short* C = Cbase + (size_t)z * (NB * SS * EE / 1);  // 8388608 elems? no: NB*SS*DK*NH
    // NB*SS*EE == 8*1024*1024 == 8388608 (each projected tensor)
    const float sc = (z == 0) ? qscale : 1.0f;
    const int tid = threadIdx.x;
    const int n0 = blockIdx.x * 64;
    const int m0 = blockIdx.y * 64;
    const int rh = tid >> 4, lq = tid & 15;
    const int ty = tid >> 4, tx = tid & 15;

    float acc[4][4] = {};
    #pragma unroll
    for (int rr = 0; rr < 4; ++rr) {
        const int row = rr * 16 + rh;
        const float4 av = *(const float4*)(A + (size_t)(m0 + row) * DK + lq * 4);
        const float4 wv = *(const float4*)(W + (size_t)(n0 + row) * DK + lq * 4);
        At[lq*4+0][row] = av.x; At[lq*4+1][row] = av.y;
        At[lq*4+2][row] = av.z; At[lq*4+3][row] = av.w;
        Bt[lq*4+0][row] = wv.x; Bt[lq*4+1][row] = wv.y;
        Bt[lq*4+2][row] = wv.z; Bt[lq*4+3][row] = wv.w;
    }
    __syncthreads();
    #pragma unroll 8
    for (int c = 0; c < 64; ++c) {
        const float4 a4 = *(const float4*)&At[c][ty * 4];
        const float4 b4 = *(const float4*)&Bt[c][tx * 4];
        const float av2[4] = {a4.x, a4.y, a4.z, a4.w};
        const float bv2[4] = {b4.x, b4.y, b4.z, b4.w};
        #pragma unroll
        for (int i = 0; i < 4; ++i)
            #pragma unroll
            for (int j = 0; j < 4; ++j)
                acc[i][j] = fmaf(av2[i], bv2[j], acc[i][j]);
    }
    const float4 bv = *(const float4*)(bias + n0 + tx * 4);
    const float bb[4] = {bv.x, bv.y, bv.z, bv.w};
    #pragma unroll
    for (int i = 0; i < 4; ++i) {
        const int r = m0 + ty * 4 + i;
        const int n = n0 + tx * 4;
        const size_t idx = ((size_t)((r >> 10) * NH + (n >> 6))) * 65536
                         + (size_t)(r & 1023) * 64 + (n & 63);
        ushort4 o;
        o.x = f2bf((acc[i][0] + bb[0]) * sc); o.y = f2bf((acc[i][1] + bb[1]) * sc);
        o.z = f2bf((acc[i][2] + bb[2]) * sc); o.w = f2bf((acc[i][3] + bb[3]) * sc);
        *(ushort4*)(C + idx) = o;
    }
}

// ---------------------------------------------------------------------------
// f32 -> bf16 conversion (for W1, W2)
// ---------------------------------------------------------------------------
__global__ __launch_bounds__(256) void cvt_bf16(
    const float* __restrict__ s, unsigned short* __restrict__ d, int n)
{
    const int i = (blockIdx.x * 256 + threadIdx.x) * 8;
    if (i >= n) return;
    const float4 a = *(const float4*)(s + i);
    const float4 b = *(const float4*)(s + i + 4);
    bf16x8 o;
    o[0]=(short)f2bf(a.x); o[1]=(short)f2bf(a.y); o[2]=(short)f2bf(a.z); o[3]=(short)f2bf(a.w);
    o[4]=(short)f2bf(b.x); o[5]=(short)f2bf(b.y); o[6]=(short)f2bf(b.z); o[7]=(short)f2bf(b.w);
    *(bf16x8*)(d + i) = o;
}

// ---------------------------------------------------------------------------
// Vp[b][h][s][d] -> Vt[b][h][d][s]  (bf16, per-head 1024x64 -> 64x1024)
// ---------------------------------------------------------------------------
__global__ __launch_bounds__(256) void transpose_v(
    const unsigned short* __restrict__ Vp, unsigned short* __restrict__ Vt)
{
    __shared__ __align__(16) unsigned short T[64][72];
    const int bh = blockIdx.y;
    const int s0 = blockIdx.x * 64;
    const size_t base = (size_t)bh * (SS * DK);
    const int tid = threadIdx.x;
    #pragma unroll
    for (int i = 0; i < 2; ++i) {
        const int c = i * 256 + tid;
        const int row = c >> 3, cq = (c & 7) * 8;
        *(bf16x8*)&T[row][cq] = *(const bf16x8*)(Vp + base + (size_t)(s0 + row) * DK + cq);
    }
    __syncthreads();
    #pragma unroll
    for (int i = 0; i < 2; ++i) {
        const int c = i * 256 + tid;
        const int d = c >> 3, sq = (c & 7) * 8;
        bf16x8 v;
        #pragma unroll
        for (int j = 0; j < 8; ++j) v[j] = (short)T[sq + j][d];
        *(bf16x8*)(Vt + base + (size_t)d * SS + s0 + sq) = v;
    }
}

// ---------------------------------------------------------------------------
// Flash attention, bf16 MFMA, SWAPPED QK^T (T12-style, 16x16 shape).
// Block = (b,h) x 64 q-rows, 4 waves (16 q each). KV tiles of 64.
// sacc = mfma(K, Q) -> S^T: lane holds k = 16*nb + 4*lg + r, q = lr.
//   -> softmax k-reduction is 15 in-lane ops + 2 shfl_xor (16, 32).
// Q is pre-scaled by 0.125*log2(e), so p = v_exp_f32(s - m) directly.
// P packed to bf16 via v_cvt_pk_bf16_f32, stored as 4x ds_write_b64
// (bank pattern <=2-way, free) into P[q][k]; PV reads it as the A-operand
// exactly like before (layout and epilogue unchanged).
// ---------------------------------------------------------------------------
__global__ __launch_bounds__(256) void attn_mfma(
    const unsigned short* __restrict__ Qp, const unsigned short* __restrict__ Kp,
    const unsigned short* __restrict__ Vt, unsigned short* __restrict__ Y)
{
    __shared__ __align__(16) unsigned short Qs[64][72];
    __shared__ __align__(16) unsigned short Ks[64][72];
    __shared__ __align__(16) unsigned short Vs[64][72];    // Vt rows: [d][k]
    __shared__ __align__(16) unsigned short Ps[4][16][72]; // per-wave P [q][k]
    const int tid  = threadIdx.x;
    const int lane = tid & 63;
    const int w    = tid >> 6;
    const int q0   = blockIdx.x * 64;
    const size_t base = (size_t)(blockIdx.z * NH + blockIdx.y) * (SS * DK);
    const int lr = lane & 15, lg = lane >> 4;
    const int lg4 = lg * 4;

    #pragma unroll
    for (int i = 0; i < 2; ++i) {
        const int c = i * 256 + tid;
        const int row = c >> 3, cq = (c & 7) * 8;
        *(bf16x8*)&Qs[row][cq] = *(const bf16x8*)(Qp + base + (size_t)(q0 + row) * DK + cq);
    }
    __syncthreads();
    // B-operand Q fragments (hoisted; per-wave q rows w*16 .. w*16+15)
    const bf16x8 bQ0 = *(const bf16x8*)&Qs[w * 16 + lr][lg * 8];
    const bf16x8 bQ1 = *(const bf16x8*)&Qs[w * 16 + lr][32 + lg * 8];

    float m = -1e30f, l = 0.0f;       // per-lane state for q = lr (x4 copies)
    f32x4 oacc[4] = {};               // O[q=lg4+r][d=16*d0+lr]

    for (int kt = 0; kt < 16; ++kt) {
        __syncthreads();   // previous tile's readers done
        #pragma unroll
        for (int i = 0; i < 2; ++i) {
            const int c = i * 256 + tid;
            const int row = c >> 3, cq = (c & 7) * 8;
            *(bf16x8*)&Ks[row][cq] = *(const bf16x8*)(Kp + base + (size_t)(kt * 64 + row) * DK + cq);
            *(bf16x8*)&Vs[row][cq] = *(const bf16x8*)(Vt + base + (size_t)row * SS + kt * 64 + cq);
        }
        __syncthreads();

        // --- QK^T (swapped): sacc[nb] = S^T[16 k-rows][16 q] ---
        f32x4 sacc[4];
        #pragma unroll
        for (int nb = 0; nb < 4; ++nb) {
            f32x4 z = {};
            const bf16x8 aK0 = *(const bf16x8*)&Ks[nb * 16 + lr][lg * 8];
            const bf16x8 aK1 = *(const bf16x8*)&Ks[nb * 16 + lr][32 + lg * 8];
            z = __builtin_amdgcn_mfma_f32_16x16x32_bf16(aK0, bQ0, z, 0, 0, 0);
            z = __builtin_amdgcn_mfma_f32_16x16x32_bf16(aK1, bQ1, z, 0, 0, 0);
            sacc[nb] = z;
        }

        // --- online softmax over k (base-2 domain; scale pre-folded into Q) ---
        float mx = sacc[0][0];
        #pragma unroll
        for (int nb = 0; nb < 4; ++nb)
            #pragma unroll
            for (int r = 0; r < 4; ++r)
                mx = fmaxf(mx, sacc[nb][r]);
        mx = fmaxf(mx, __shfl_xor(mx, 16));
        mx = fmaxf(mx, __shfl_xor(mx, 32));
        const float mn = fmaxf(m, mx);
        const float alpha = exp2_hw(m - mn);
        float p[4][4];
        float ls = 0.0f;
        #pragma unroll
        for (int nb = 0; nb < 4; ++nb)
            #pragma unroll
            for (int r = 0; r < 4; ++r) {
                const float pv = exp2_hw(sacc[nb][r] - mn);
                p[nb][r] = pv;
                ls += pv;
            }
        ls += __shfl_xor(ls, 16);
        ls += __shfl_xor(ls, 32);
        l = l * alpha + ls;
        m = mn;

        // --- rescale O rows by their alpha (broadcast from lane q=lg4+r) ---
        #pragma unroll
        for (int r = 0; r < 4; ++r) {
            const float ar = __shfl(alpha, lg4 + r, 16);
            #pragma unroll
            for (int d0 = 0; d0 < 4; ++d0) oacc[d0][r] *= ar;
        }

        // --- pack P to bf16, wide LDS stores: P[q=lr][k=16nb+lg4 .. +3] ---
        #pragma unroll
        for (int nb = 0; nb < 4; ++nb) {
            uint2 pw;
            pw.x = cvt_pk_bf16(p[nb][0], p[nb][1]);
            pw.y = cvt_pk_bf16(p[nb][2], p[nb][3]);
            *(uint2*)&Ps[w][lr][nb * 16 + lg4] = pw;
        }
        // same-wave write->read: compiler inserts lgkmcnt wait, no barrier needed

        // --- PV: O[16q][64d] += P[16][64] x V[64][64] ---
        #pragma unroll
        for (int kk = 0; kk < 2; ++kk) {
            const bf16x8 aP = *(const bf16x8*)&Ps[w][lr][kk * 32 + lg * 8];
            #pragma unroll
            for (int d0 = 0; d0 < 4; ++d0) {
                const bf16x8 bv = *(const bf16x8*)&Vs[d0 * 16 + lr][kk * 32 + lg * 8];
                oacc[d0] = __builtin_amdgcn_mfma_f32_16x16x32_bf16(aP, bv, oacc[d0], 0, 0, 0);
            }
        }
    }

    // epilogue: Y[b][s][h*64+d] bf16; 1/l broadcast like alpha
    const float linv = 1.0f / l;
    #pragma unroll
    for (int r = 0; r < 4; ++r) {
        const float lri = __shfl(linv, lg4 + r, 16);
        const int qrow = q0 + w * 16 + lg4 + r;
        unsigned short* dst = Y + (size_t)(blockIdx.z * SS + qrow) * EE + blockIdx.y * DK;
        #pragma unroll
        for (int d0 = 0; d0 < 4; ++d0)
            dst[d0 * 16 + lr] = f2bf(oacc[d0][r] * lri);
    }
}

// ---------------------------------------------------------------------------
// MLP GEMM, bf16 MFMA: C[M,N] = A[M,K]_bf16 @ B[N,K]_bf16^T + bias (+ReLU)
// 128x128 tile, 4 waves (2x2 of 64x64), K-step 64, reg-staged padded LDS.
// ---------------------------------------------------------------------------
template<bool RELU, bool OUT_BF16>
__global__ __launch_bounds__(256) void mlp_gemm(
    const unsigned short* __restrict__ A, const unsigned short* __restrict__ B,
    const float* __restrict__ bias, void* __restrict__ Cv)
{
    const int K = 1024, N = 1024;
    __shared__ __align__(16) unsigned short As[128][72];
    __shared__ __align__(16) unsigned short Bs[128][72];
    const int tid  = threadIdx.x;
    const int lane = tid & 63;
    const int w = tid >> 6, wm = w >> 1, wn = w & 1;
    const int n0 = blockIdx.x * 128, m0 = blockIdx.y * 128;
    const int lr = lane & 15, lg = lane >> 4;

    f32x4 acc[4][4] = {};

    for (int kt = 0; kt < K; kt += 64) {
        __syncthreads();
        #pragma unroll
        for (int i = 0; i < 4; ++i) {
            const int c = i * 256 + tid;       // 0..1023
            const int row = c >> 3, cq = (c & 7) * 8;
            *(bf16x8*)&As[row][cq] = *(const bf16x8*)(A + (size_t)(m0 + row) * K + kt + cq);
            *(bf16x8*)&Bs[row][cq] = *(const bf16x8*)(B + (size_t)(n0 + row) * K + kt + cq);
        }
        __syncthreads();
        #pragma unroll
        for (int kk = 0; kk < 2; ++kk) {
            bf16x8 af[4], bfr[4];
            #pragma unroll
            for (int mf = 0; mf < 4; ++mf)
                af[mf] = *(const bf16x8*)&As[wm * 64 + mf * 16 + lr][kk * 32 + lg * 8];
            #pragma unroll
            for (int nf = 0; nf < 4; ++nf)
                bfr[nf] = *(const bf16x8*)&Bs[wn * 64 + nf * 16 + lr][kk * 32 + lg * 8];
            #pragma unroll
            for (int mf = 0; mf < 4; ++mf)
                #pragma unroll
                for (int nf = 0; nf < 4; ++nf)
                    acc[mf][nf] = __builtin_amdgcn_mfma_f32_16x16x32_bf16(
                        af[mf], bfr[nf], acc[mf][nf], 0, 0, 0);
        }
    }

    #pragma unroll
    for (int nf = 0; nf < 4; ++nf) {
        const int cc = n0 + wn * 64 + nf * 16 + lr;
        const float bb = bias[cc];
        #pragma unroll
        for (int mf = 0; mf < 4; ++mf) {
            #pragma unroll
            for (int r = 0; r < 4; ++r) {
                float x = acc[mf][nf][r] + bb;
                if (RELU) x = fmaxf(x, 0.0f);
                const size_t rr = (size_t)(m0 + wm * 64 + mf * 16 + lg * 4 + r);
                if (OUT_BF16) ((unsigned short*)Cv)[rr * N + cc] = f2bf(x);
                else          ((float*)Cv)[rr * N + cc] = x;
            }
        }
    }
}

// ---------------------------------------------------------------------------
// Workspace layout (ushort elements; 8.4M elems = 16.78 MB per tensor):
//   Qp : [0        , 8388608 )   -> reused as H1 after attention
//   Kp : [8388608  , 16777216)
//   Vp : [16777216 , 25165824)   -> reused as Y after transpose
//   Vt : [25165824 , 33554432)
//   W1b: [33554432 , 34603008)
//   W2b: [34603008 , 35651584)
// ---------------------------------------------------------------------------
extern "C" void kernel_launch(void* const* d_in, const int* in_sizes, int n_in,
                              void* d_out, int out_size, void* d_ws, size_t ws_size,
                              hipStream_t stream) {
    const float* q  = (const float*)d_in[0];
    const float* k  = (const float*)d_in[1];
    const float* v  = (const float*)d_in[2];
    const float* Wq = (const float*)d_in[3];
    const float* bq = (const float*)d_in[4];
    const float* W1 = (const float*)d_in[5];
    const float* b1 = (const float*)d_in[6];
    const float* W2 = (const float*)d_in[7];
    const float* b2 = (const float*)d_in[8];

    unsigned short* wsu = (unsigned short*)d_ws;
    unsigned short* Qp  = wsu;                       // z=0 of proj output
    unsigned short* Kp  = wsu + (size_t)8388608;
    unsigned short* Vp  = wsu + (size_t)16777216;
    unsigned short* Vt  = wsu + (size_t)25165824;
    unsigned short* W1b = wsu + (size_t)33554432;
    unsigned short* W2b = wsu + (size_t)34603008;
    unsigned short* Y   = Vp;   // Vp dead after transpose
    unsigned short* H1  = Qp;   // Qp dead after attention

    dim3 blk(256);

    // folds 1/sqrt(dk)=0.125 and log2(e) into Q so attn uses v_exp_f32 directly
    const float qscale = 0.125f * 1.44269504088896340736f;
    dim3 gp(EE / 64, (NB * SS) / 64, 3);
    proj_gemm<<<gp, blk, 0, stream>>>(q, k, v, Wq, bq, Qp, qscale);

    cvt_bf16<<<512, blk, 0, stream>>>(W1, W1b, DMOD * EE);
    cvt_bf16<<<512, blk, 0, stream>>>(W2, W2b, DMOD * DMOD);

    transpose_v<<<dim3(16, 128), blk, 0, stream>>>(Vp, Vt);

    attn_mfma<<<dim3(16, 16, 8), blk, 0, stream>>>(Qp, Kp, Vt, Y);

    mlp_gemm<true,  true ><<<dim3(8, 64), blk, 0, stream>>>(Y,  W1b, b1, H1);
    mlp_gemm<false, false><<<dim3(8, 64), blk, 0, stream>>>(H1, W2b, b2, d_out);
}